// Round 8
// baseline (3822.667 us; speedup 1.0000x reference)
//
#include <hip/hip_runtime.h>

// Problem constants: B=8, N=16384, S=1024, T=2, D=3
#define NPTS 16384
#define SPTS 1024

typedef _Float16 half8 __attribute__((ext_vector_type(8)));
typedef float float16 __attribute__((ext_vector_type(16)));

union H8 { _Float16 h[8]; half8 v; uint4 q4; };

// min across each 32-lane half (validated r6/r7, absmax 0)
__device__ inline float wave32_min(float v) {
    v = fminf(v, __int_as_float(__builtin_amdgcn_mov_dpp(__float_as_int(v), 0xB1, 0xF, 0xF, true)));
    v = fminf(v, __int_as_float(__builtin_amdgcn_mov_dpp(__float_as_int(v), 0x4E, 0xF, 0xF, true)));
    v = fminf(v, __int_as_float(__builtin_amdgcn_mov_dpp(__float_as_int(v), 0x141, 0xF, 0xF, true)));
    v = fminf(v, __int_as_float(__builtin_amdgcn_mov_dpp(__float_as_int(v), 0x140, 0xF, 0xF, true)));
    v = fminf(v, __int_as_float(__builtin_amdgcn_ds_swizzle(__float_as_int(v), 0x401F)));
    return v;
}

// D[m][n] = A(gt)[m]·B(sp)[n], A=[x,y,z,|q|^2,1,0..], B=[-2x',-2y',-2z',1,|p'|^2,0..]
// (exact sq-distance via one 32x32x16 f16 MFMA, fp32 accumulate; validated r6/r7).
// B-frag LDS: 32 tiles, stride 33 uint4 (32 lanes*16B + zero slot for lanes 32..63).
// C layout: col=lane&31, row=(reg&3)+8*(reg>>2)+4*(lane>>5).

__global__ __launch_bounds__(256, 4) void fused_kernel(
    const float* __restrict__ gt,   // [8,16384,3]
    const float* __restrict__ sp,   // [8,1024,3]
    const float* __restrict__ tgt,  // [16,16384,3]
    const float* __restrict__ tsp,  // [16,1024,3]
    const float* __restrict__ tm,   // [2,3,3]
    float* __restrict__ accum,
    unsigned int* __restrict__ minarr,  // fallback path
    float* __restrict__ slab,           // [24][32][1024] per-block col-mins
    int use_slab)
{
    const int bid = blockIdx.x;
    const int tid = threadIdx.x;
    const int lane = tid & 63;
    const int lh = lane & 31;
    const int w = tid >> 6;

    if (bid >= 768) {
        // ---------------- consistency MSE (fp32 exact) ----------------
        int idx = (bid - 768) * 256 + tid;  // over (t,b,s) = 2*8*1024
        int t = idx >> 13;
        int bs = idx & 8191;
        const float* p = sp + (size_t)bs * 3;
        float x = p[0], y = p[1], z = p[2];
        const float* m = tm + t * 9;
        const float* q = tsp + (size_t)idx * 3;
        float acc = 0.f;
#pragma unroll
        for (int e = 0; e < 3; e++) {
            float v = fmaf(x, m[e], fmaf(y, m[3 + e], z * m[6 + e]));
            float d = v - q[e];
            acc = fmaf(d, d, acc);
        }
        for (int o = 32; o > 0; o >>= 1) acc += __shfl_down(acc, o, 64);
        if ((tid & 63) == 0)
            atomicAdd(accum, acc * (1000.f / (2.f * 8.f * 1024.f * 3.f)));
        return;
    }

    // ---------------- fused chamfer: one D matrix, both mins ----------------
    int bb = bid >> 5;         // 24 batches
    int mc = bid & 31;         // 512-row gt chunk
    const float* spp = (bb < 8) ? sp + (size_t)bb * SPTS * 3
                                : tsp + (size_t)(bb - 8) * SPTS * 3;
    const float* qp  = (bb < 8) ? gt + (size_t)bb * NPTS * 3
                                : tgt + (size_t)(bb - 8) * NPTS * 3;

    __shared__ uint4 s_frag4[1056];  // 32 tiles * 33 uint4 = 16.9 KB

    // A-frags for this wave's 4 m-tiles, straight from global into registers
    H8 a[4];
#pragma unroll
    for (int mi = 0; mi < 4; mi++) {
        int mt = w * 4 + mi;
        a[mi].q4 = make_uint4(0, 0, 0, 0);
        if (lane < 32) {
            const float* pp = qp + (size_t)(mc * 512 + mt * 32 + lh) * 3;
            float x = pp[0], y = pp[1], z = pp[2];
            a[mi].h[0] = (_Float16)x; a[mi].h[1] = (_Float16)y; a[mi].h[2] = (_Float16)z;
            a[mi].h[3] = (_Float16)(x * x + y * y + z * z); a[mi].h[4] = (_Float16)1.f;
        }
    }

    // stage sp B-frags (1024 points) + zero slots
    if (tid < 32) s_frag4[tid * 33 + 32] = make_uint4(0, 0, 0, 0);
    for (int i = tid; i < 1024; i += 256) {
        const float* pp = spp + (size_t)i * 3;
        float sx = pp[0], sy = pp[1], sz = pp[2];
        H8 bf; bf.q4 = make_uint4(0, 0, 0, 0);
        bf.h[0] = (_Float16)(-2.f * sx); bf.h[1] = (_Float16)(-2.f * sy);
        bf.h[2] = (_Float16)(-2.f * sz); bf.h[3] = (_Float16)1.f;
        bf.h[4] = (_Float16)(sx * sx + sy * sy + sz * sz);
        s_frag4[(i >> 5) * 33 + (i & 31)] = bf.q4;
    }
    __syncthreads();

    const char* fb = (const char*)s_frag4 + ((lane < 32) ? lh * 16 : 512);
    float16 z16 = {0.f,0.f,0.f,0.f,0.f,0.f,0.f,0.f,0.f,0.f,0.f,0.f,0.f,0.f,0.f,0.f};
    float cm[32];
#pragma unroll
    for (int t = 0; t < 32; t++) cm[t] = 1e30f;
    float wsum = 0.f;

#pragma unroll
    for (int mi = 0; mi < 4; mi++) {
        float rm[16];
#pragma unroll
        for (int r = 0; r < 16; r++) rm[r] = 1e30f;
        H8 b0; b0.q4 = *(const uint4*)(fb);  // 2-deep pipeline: prefetch t+1
#pragma unroll
        for (int t = 0; t < 32; t++) {
            H8 bn;
            if (t < 31) bn.q4 = *(const uint4*)(fb + (t + 1) * 528);
            float16 d = __builtin_amdgcn_mfma_f32_32x32x16_f16(a[mi].v, b0.v, z16, 0, 0, 0);
#pragma unroll
            for (int r = 0; r < 16; r++) rm[r] = fminf(rm[r], d[r]);
            // col-min tree over this lane's 16 rows
            float e0 = fminf(d[0], d[1]),  e1 = fminf(d[2], d[3]);
            float e2 = fminf(d[4], d[5]),  e3 = fminf(d[6], d[7]);
            float e4 = fminf(d[8], d[9]),  e5 = fminf(d[10], d[11]);
            float e6 = fminf(d[12], d[13]), e7 = fminf(d[14], d[15]);
            float f0 = fminf(e0, e1), f1 = fminf(e2, e3);
            float f2 = fminf(e4, e5), f3 = fminf(e6, e7);
            cm[t] = fminf(cm[t], fminf(fminf(f0, f1), fminf(f2, f3)));
            b0 = bn;
        }
        float tsum = 0.f;
#pragma unroll
        for (int r = 0; r < 16; r++) tsum += wave32_min(rm[r]);
        wsum += tsum;
    }
    wsum += __shfl_xor(wsum, 32, 64);
    if (lane == 0) {
        float scale = (bb < 8) ? 1.f / (2.f * 3.f * 8.f * 16384.f)
                               : 1.f / (2.f * 3.f * 16.f * 16384.f);
        atomicAdd(accum, wsum * scale);
    }

    // ---- block-level col-min combine -> private slab (plain stores) ----
    __syncthreads();
    float* colbuf = (float*)s_frag4;  // overlay, 4096 floats
#pragma unroll
    for (int t = 0; t < 32; t++) {
        float v = fminf(cm[t], __shfl_xor(cm[t], 32, 64));  // merge row-halves
        if (lane < 32) colbuf[(w * 32 + t) * 32 + lh] = v;
    }
    __syncthreads();
#pragma unroll
    for (int k = 0; k < 4; k++) {
        int e = k * 256 + tid;  // e = t*32 + col
        int t = e >> 5, col = e & 31;
        float v = fminf(fminf(colbuf[(0 * 32 + t) * 32 + col], colbuf[(1 * 32 + t) * 32 + col]),
                        fminf(colbuf[(2 * 32 + t) * 32 + col], colbuf[(3 * 32 + t) * 32 + col]));
        if (use_slab)
            slab[((size_t)(bb * 32 + mc)) * 1024 + e] = v;
        else
            atomicMin(&minarr[bb * SPTS + e], __float_as_uint(fmaxf(v, 0.f)));
    }
}

// 96 blocks x 256: each thread owns one (bb,e); min over 32 slabs, scale, sum -> accum
__global__ __launch_bounds__(256) void reduce_kernel(
    const unsigned int* __restrict__ minarr,
    const float* __restrict__ slab,
    float* __restrict__ accum,
    int use_slab)
{
    int eg = blockIdx.x * 256 + threadIdx.x;  // 0..24575
    int bb = eg >> 10, e = eg & 1023;
    float v;
    if (use_slab) {
        v = 1e30f;
#pragma unroll 8
        for (int k = 0; k < 32; k++)
            v = fminf(v, slab[((size_t)(bb * 32 + k)) * 1024 + e]);
    } else {
        v = __uint_as_float(minarr[eg]);
    }
    float scale = (bb < 8) ? 1.f / (2.f * 3.f * 8.f * 1024.f)
                           : 1.f / (2.f * 3.f * 16.f * 1024.f);
    float s = v * scale;
    for (int o = 32; o > 0; o >>= 1) s += __shfl_down(s, o, 64);
    if ((threadIdx.x & 63) == 0) atomicAdd(accum, s);
}

__global__ void out_kernel(const float* __restrict__ accum, float* __restrict__ out)
{
    if (threadIdx.x == 0) out[0] = accum[0];
}

extern "C" void kernel_launch(void* const* d_in, const int* in_sizes, int n_in,
                              void* d_out, int out_size, void* d_ws, size_t ws_size,
                              hipStream_t stream) {
    const float* gt  = (const float*)d_in[0];  // gt_points [8,16384,3]
    const float* sp  = (const float*)d_in[1];  // structure_points [8,1024,3]
    const float* tgt = (const float*)d_in[2];  // transed_gt_points [2,8,16384,3]
    const float* tsp = (const float*)d_in[3];  // transed_structure_points [2,8,1024,3]
    const float* tm  = (const float*)d_in[4];  // trans_mats [2,3,3]
    float* out = (float*)d_out;

    float* accum = (float*)d_ws;
    unsigned int* minarr = (unsigned int*)((char*)d_ws + 64);
    size_t slab_off = 64 + (size_t)24 * 1024 * 4;
    float* slab = (float*)((char*)d_ws + slab_off);
    size_t need = slab_off + (size_t)24 * 32 * 1024 * 4;
    int use_slab = (ws_size >= need) ? 1 : 0;  // constant across calls (graph-safe)

    hipMemsetAsync(accum, 0, 64, stream);
    if (!use_slab)
        hipMemsetAsync(minarr, 0x7F, 24 * 1024 * sizeof(unsigned int), stream);

    fused_kernel<<<832, 256, 0, stream>>>(gt, sp, tgt, tsp, tm, accum, minarr, slab, use_slab);
    reduce_kernel<<<96, 256, 0, stream>>>(minarr, slab, accum, use_slab);
    out_kernel<<<1, 64, 0, stream>>>(accum, out);
}

// Round 9
// 156.333 us; speedup vs baseline: 24.4522x; 24.4522x over previous
//
#include <hip/hip_runtime.h>

// Problem constants: B=8, N=16384, S=1024, T=2, D=3
#define NPTS 16384
#define SPTS 1024

typedef _Float16 half8 __attribute__((ext_vector_type(8)));
typedef float float16 __attribute__((ext_vector_type(16)));

union H8 { _Float16 h[8]; half8 v; uint4 q4; };

// min across each 32-lane half (validated r6/r7, absmax 0)
__device__ inline float wave32_min(float v) {
    v = fminf(v, __int_as_float(__builtin_amdgcn_mov_dpp(__float_as_int(v), 0xB1, 0xF, 0xF, true)));
    v = fminf(v, __int_as_float(__builtin_amdgcn_mov_dpp(__float_as_int(v), 0x4E, 0xF, 0xF, true)));
    v = fminf(v, __int_as_float(__builtin_amdgcn_mov_dpp(__float_as_int(v), 0x141, 0xF, 0xF, true)));
    v = fminf(v, __int_as_float(__builtin_amdgcn_mov_dpp(__float_as_int(v), 0x140, 0xF, 0xF, true)));
    v = fminf(v, __int_as_float(__builtin_amdgcn_ds_swizzle(__float_as_int(v), 0x401F)));
    return v;
}

// D[m][n] = A(gt)[m]·B(sp)[n], A=[x,y,z,|q|^2,1,0..], B=[-2x',-2y',-2z',1,|p'|^2,0..]
// One 32x32x16 f16 MFMA = 1024 exact sq-distances (fp32 accumulate; validated r6/r7).
// Frag LDS: per 32-point tile, 33 uint4 (32 lanes*16B + zero slot for lanes 32..63).
// C layout: col=lane&31, row=(reg&3)+8*(reg>>2)+4*(lane>>5).
// NOTE (r8 lesson): register ceiling is binding. (256,3) -> 84 VGPR, no spill.
// (256,4) + extra live frags -> 64 VGPR + scratch spill -> 13.5 GB traffic, 45x slower.

__global__ __launch_bounds__(256, 3) void fused_kernel(
    const float* __restrict__ gt,   // [8,16384,3]
    const float* __restrict__ sp,   // [8,1024,3]
    const float* __restrict__ tgt,  // [16,16384,3]
    const float* __restrict__ tsp,  // [16,1024,3]
    const float* __restrict__ tm,   // [2,3,3]
    float* __restrict__ accum,
    unsigned int* __restrict__ minarr,  // fallback path
    float* __restrict__ slab,           // [24][32][1024] per-block col-mins
    int use_slab)
{
    const int bid = blockIdx.x;
    const int tid = threadIdx.x;
    const int lane = tid & 63;
    const int lh = lane & 31;
    const int w = tid >> 6;  // wave 0..3

    __shared__ uint4 s_frag4[1584];  // sp frags [0,1056) + gt frags [1056,1584) = 25.3 KB

    if (bid >= 768) {
        // ---------------- consistency MSE (fp32 exact), tail blocks ----------------
        int idx = (bid - 768) * 256 + tid;  // over (t,b,s) = 2*8*1024
        int t = idx >> 13;
        int bs = idx & 8191;
        const float* p = sp + (size_t)bs * 3;
        float x = p[0], y = p[1], z = p[2];
        const float* m = tm + t * 9;
        const float* q = tsp + (size_t)idx * 3;
        float acc = 0.f;
#pragma unroll
        for (int e = 0; e < 3; e++) {
            float v = fmaf(x, m[e], fmaf(y, m[3 + e], z * m[6 + e]));
            float d = v - q[e];
            acc = fmaf(d, d, acc);
        }
        for (int o = 32; o > 0; o >>= 1) acc += __shfl_down(acc, o, 64);
        if ((tid & 63) == 0)
            atomicAdd(accum, acc * (1000.f / (2.f * 8.f * 1024.f * 3.f)));
        return;
    }

    // ---------------- fused chamfer: one D matrix, both mins ----------------
    int bb = bid >> 5;         // 24 batches
    int mc = bid & 31;         // 512-row gt chunk
    const float* spp = (bb < 8) ? sp + (size_t)bb * SPTS * 3
                                : tsp + (size_t)(bb - 8) * SPTS * 3;
    const float* qp  = (bb < 8) ? gt + (size_t)bb * NPTS * 3
                                : tgt + (size_t)(bb - 8) * NPTS * 3;

    // zero slots for all 48 tiles (32 sp + 16 gt): index t*33+32
    if (tid < 48) s_frag4[tid * 33 + 32] = make_uint4(0, 0, 0, 0);
    // stage sp B-frags (1024 points)
    for (int i = tid; i < 1024; i += 256) {
        const float* pp = spp + (size_t)i * 3;
        float sx = pp[0], sy = pp[1], sz = pp[2];
        H8 bf; bf.q4 = make_uint4(0, 0, 0, 0);
        bf.h[0] = (_Float16)(-2.f * sx); bf.h[1] = (_Float16)(-2.f * sy);
        bf.h[2] = (_Float16)(-2.f * sz); bf.h[3] = (_Float16)1.f;
        bf.h[4] = (_Float16)(sx * sx + sy * sy + sz * sz);
        s_frag4[(i >> 5) * 33 + (i & 31)] = bf.q4;
    }
    // stage gt A-frags (512 points of this chunk)
    for (int i = tid; i < 512; i += 256) {
        const float* pp = qp + (size_t)(mc * 512 + i) * 3;
        float x = pp[0], y = pp[1], z = pp[2];
        H8 af; af.q4 = make_uint4(0, 0, 0, 0);
        af.h[0] = (_Float16)x; af.h[1] = (_Float16)y; af.h[2] = (_Float16)z;
        af.h[3] = (_Float16)(x * x + y * y + z * z); af.h[4] = (_Float16)1.f;
        s_frag4[1056 + (i >> 5) * 33 + (i & 31)] = af.q4;
    }
    __syncthreads();

    const char* lds = (const char*)s_frag4;
    const int laneoff = (lane < 32) ? lh * 16 : 512;
    const char* bBase = lds + laneoff;
    const char* aBase = lds + 1056 * 16 + laneoff;

    float16 z16 = {0.f,0.f,0.f,0.f,0.f,0.f,0.f,0.f,0.f,0.f,0.f,0.f,0.f,0.f,0.f,0.f};
    float cm[32];
#pragma unroll
    for (int t = 0; t < 32; t++) cm[t] = 1e30f;
    float wsum = 0.f;

    for (int mi = 0; mi < 4; mi++) {
        int mt = w * 4 + mi;  // this wave's m-tile (0..15)
        H8 a; a.q4 = *(const uint4*)(aBase + mt * 528);
        float rm[16];
#pragma unroll
        for (int r = 0; r < 16; r++) rm[r] = 1e30f;
#pragma unroll
        for (int t = 0; t < 32; t++) {
            H8 b; b.q4 = *(const uint4*)(bBase + t * 528);
            float16 d = __builtin_amdgcn_mfma_f32_32x32x16_f16(a.v, b.v, z16, 0, 0, 0);
            // row-min accumulate (gt side)
#pragma unroll
            for (int r = 0; r < 16; r++) rm[r] = fminf(rm[r], d[r]);
            // col-min tree (sp side) over this lane's 16 rows
            float e0 = fminf(d[0], d[1]),  e1 = fminf(d[2], d[3]);
            float e2 = fminf(d[4], d[5]),  e3 = fminf(d[6], d[7]);
            float e4 = fminf(d[8], d[9]),  e5 = fminf(d[10], d[11]);
            float e6 = fminf(d[12], d[13]), e7 = fminf(d[14], d[15]);
            float f0 = fminf(e0, e1), f1 = fminf(e2, e3);
            float f2 = fminf(e4, e5), f3 = fminf(e6, e7);
            cm[t] = fminf(cm[t], fminf(fminf(f0, f1), fminf(f2, f3)));
        }
        float tsum = 0.f;
#pragma unroll
        for (int r = 0; r < 16; r++) tsum += wave32_min(rm[r]);
        wsum += tsum;
    }
    wsum += __shfl_xor(wsum, 32, 64);
    if (lane == 0) {
        float scale = (bb < 8) ? 1.f / (2.f * 3.f * 8.f * 16384.f)
                               : 1.f / (2.f * 3.f * 16.f * 16384.f);
        atomicAdd(accum, wsum * scale);
    }

    // ---- block-level col-min combine -> private slab (plain coalesced stores) ----
    __syncthreads();
    float* colbuf = (float*)s_frag4;  // overlay sp-frag region (4096 floats)
#pragma unroll
    for (int t = 0; t < 32; t++) {
        float v = fminf(cm[t], __shfl_xor(cm[t], 32, 64));  // merge row-halves
        if (lane < 32) colbuf[(w * 32 + t) * 32 + lh] = v;
    }
    __syncthreads();
#pragma unroll
    for (int k = 0; k < 4; k++) {
        int e = k * 256 + tid;  // e = t*32 + col
        int t = e >> 5, col = e & 31;
        float v = fminf(fminf(colbuf[(0 * 32 + t) * 32 + col], colbuf[(1 * 32 + t) * 32 + col]),
                        fminf(colbuf[(2 * 32 + t) * 32 + col], colbuf[(3 * 32 + t) * 32 + col]));
        if (use_slab)
            slab[((size_t)(bb * 32 + mc)) * 1024 + e] = v;
        else
            atomicMin(&minarr[bb * SPTS + e], __float_as_uint(fmaxf(v, 0.f)));
    }
}

// 96 blocks x 256: each thread owns one (bb,e); min over 32 slabs, scale, sum -> accum
__global__ __launch_bounds__(256) void reduce_kernel(
    const unsigned int* __restrict__ minarr,
    const float* __restrict__ slab,
    float* __restrict__ accum,
    int use_slab)
{
    int eg = blockIdx.x * 256 + threadIdx.x;  // 0..24575
    int bb = eg >> 10, e = eg & 1023;
    float v;
    if (use_slab) {
        v = 1e30f;
#pragma unroll 8
        for (int k = 0; k < 32; k++)
            v = fminf(v, slab[((size_t)(bb * 32 + k)) * 1024 + e]);
    } else {
        v = __uint_as_float(minarr[eg]);
    }
    float scale = (bb < 8) ? 1.f / (2.f * 3.f * 8.f * 1024.f)
                           : 1.f / (2.f * 3.f * 16.f * 1024.f);
    float s = v * scale;
    for (int o = 32; o > 0; o >>= 1) s += __shfl_down(s, o, 64);
    if ((threadIdx.x & 63) == 0) atomicAdd(accum, s);
}

__global__ void out_kernel(const float* __restrict__ accum, float* __restrict__ out)
{
    if (threadIdx.x == 0) out[0] = accum[0];
}

extern "C" void kernel_launch(void* const* d_in, const int* in_sizes, int n_in,
                              void* d_out, int out_size, void* d_ws, size_t ws_size,
                              hipStream_t stream) {
    const float* gt  = (const float*)d_in[0];  // gt_points [8,16384,3]
    const float* sp  = (const float*)d_in[1];  // structure_points [8,1024,3]
    const float* tgt = (const float*)d_in[2];  // transed_gt_points [2,8,16384,3]
    const float* tsp = (const float*)d_in[3];  // transed_structure_points [2,8,1024,3]
    const float* tm  = (const float*)d_in[4];  // trans_mats [2,3,3]
    float* out = (float*)d_out;

    float* accum = (float*)d_ws;
    unsigned int* minarr = (unsigned int*)((char*)d_ws + 64);
    size_t slab_off = 64 + (size_t)24 * 1024 * 4;
    float* slab = (float*)((char*)d_ws + slab_off);
    size_t need = slab_off + (size_t)24 * 32 * 1024 * 4;
    int use_slab = (ws_size >= need) ? 1 : 0;  // constant across calls (graph-safe)

    hipMemsetAsync(accum, 0, 64, stream);
    if (!use_slab)
        hipMemsetAsync(minarr, 0x7F, 24 * 1024 * sizeof(unsigned int), stream);

    fused_kernel<<<832, 256, 0, stream>>>(gt, sp, tgt, tsp, tm, accum, minarr, slab, use_slab);
    reduce_kernel<<<96, 256, 0, stream>>>(minarr, slab, accum, use_slab);
    out_kernel<<<1, 64, 0, stream>>>(accum, out);
}